// Round 14
// baseline (1127.399 us; speedup 1.0000x reference)
//
#include <hip/hip_runtime.h>
#include <hip/hip_bf16.h>
#include <cstdint>
#include <cstddef>

#define BATCH 4096
#define DIM   2048
#define FEAT  16384
#define MAXF  2048          // cap on flagged rows for exact kest recompute

typedef __attribute__((ext_vector_type(8))) _Float16 h8v;
typedef __attribute__((ext_vector_type(4))) float f4v;
typedef __attribute__((ext_vector_type(4))) unsigned short us4v;

__device__ __forceinline__ void split2(float v, unsigned short &h, unsigned short &l){
  _Float16 hf = (_Float16)v;
  _Float16 lf = (_Float16)((v - (float)hf) * 2048.0f);
  h = __builtin_bit_cast(unsigned short, hf);
  l = __builtin_bit_cast(unsigned short, lf);
}

__device__ __forceinline__ void gload16(const void* g, void* l){
  __builtin_amdgcn_global_load_lds(
      (const __attribute__((address_space(1))) void*)g,
      (__attribute__((address_space(3))) void*)l, 16, 0, 0);
}

// ===========================================================================
// split kernels
// ===========================================================================
__global__ __launch_bounds__(256)
void splitX(const float* __restrict__ x, const float* __restrict__ bdec,
            unsigned short* __restrict__ p0, unsigned short* __restrict__ p1)
{
  const size_t i = ((size_t)blockIdx.x * 256 + threadIdx.x) * 4;
  const int col = (int)(i & (DIM - 1));
  const float4 v = *(const float4*)(x + i);
  const float4 b = *(const float4*)(bdec + col);
  float e0 = v.x - b.x, e1 = v.y - b.y, e2 = v.z - b.z, e3 = v.w - b.w;
  ushort4 H, L;
  split2(e0, H.x, L.x); split2(e1, H.y, L.y);
  split2(e2, H.z, L.z); split2(e3, H.w, L.w);
  *(ushort4*)(p0 + i) = H; *(ushort4*)(p1 + i) = L;
}

__global__ __launch_bounds__(256)
void splitW(const float* __restrict__ w,
            unsigned short* __restrict__ p0, unsigned short* __restrict__ p1)
{
  const size_t i = ((size_t)blockIdx.x * 256 + threadIdx.x) * 4;
  const float4 v = *(const float4*)(w + i);
  ushort4 H, L;
  split2(v.x, H.x, L.x); split2(v.y, H.y, L.y);
  split2(v.z, H.z, L.z); split2(v.w, H.w, L.w);
  *(ushort4*)(p0 + i) = H; *(ushort4*)(p1 + i) = L;
}

// hi-plane only
__global__ __launch_bounds__(256)
void splitW1(const float* __restrict__ w, unsigned short* __restrict__ p0)
{
  const size_t i = ((size_t)blockIdx.x * 256 + threadIdx.x) * 4;
  const float4 v = *(const float4*)(w + i);
  ushort4 H;
  H.x = __builtin_bit_cast(unsigned short, (_Float16)v.x);
  H.y = __builtin_bit_cast(unsigned short, (_Float16)v.y);
  H.z = __builtin_bit_cast(unsigned short, (_Float16)v.z);
  H.w = __builtin_bit_cast(unsigned short, (_Float16)v.w);
  *(ushort4*)(p0 + i) = H;
}

// ===========================================================================
// Fused dual 1-product GEMM, gemmp-shaped (proven 56% util structure):
// 512 threads / 8 waves, wave tile 32x64; each wave computes BOTH products
// for its tile: per K-step 10 ds_reads (2 A + 4 B1 + 4 B2) -> 16 MFMA,
// acc = 2x[2][4] = 64 VGPR. A-frags shared between products.
//   acc1 -> acts16 = fp16(relu(A*B1^T + benc))
//   acc2 -> zpart  = w2-reduce(relu(A*B2^T + bk1))
// 48 KB LDS dbuf; staging layout identical to r13 (24 x 1KB chunks, 3/wave).
// ===========================================================================
__global__ __launch_bounds__(512, 4)
void gemmd(const unsigned short* __restrict__ Ah_, const unsigned short* __restrict__ B1h_,
           const unsigned short* __restrict__ B2h_,
           const float* __restrict__ benc, const float* __restrict__ bk1,
           const float* __restrict__ w2,
           _Float16* __restrict__ acts16, float* __restrict__ zpart)
{
  __shared__ unsigned short sAB[2][3][128][32];   // 48 KB: [buf][A|B1|B2]
  const int tid  = threadIdx.x;
  const int lane = tid & 63, wv = tid >> 6;       // wv 0..7

  const int bid = blockIdx.x;
  const int xcd = bid & 7;
  const int idx = bid >> 3;
  const int sq  = idx >> 6;
  const int s   = idx & 63;
  const int bx  = (xcd << 4) | ((sq & 1) << 3) | (s & 7);
  const int by  = ((sq >> 1) << 3) | (s >> 3);
  const int row0 = by << 7, col0 = bx << 7;

  // wave tile: 32 rows x 64 cols
  const int wr = (wv & 3) << 5, wc = (wv >> 2) << 6;

  f4v acc1[2][4], acc2[2][4];
  #pragma unroll
  for (int i = 0; i < 2; ++i)
    #pragma unroll
    for (int j = 0; j < 4; ++j){
      acc1[i][j] = (f4v){0.f, 0.f, 0.f, 0.f};
      acc2[i][j] = (f4v){0.f, 0.f, 0.f, 0.f};
    }

  // staging: 24 chunks of 1 KB (8 A + 8 B1 + 8 B2); 3 per wave
  const unsigned short* gsrc[3];
  unsigned ldsoff[3];
  #pragma unroll
  for (int j = 0; j < 3; ++j){
    const int q = wv * 3 + j;          // 0..23
    const int mat = q >> 3;            // 0=A, 1=B1, 2=B2
    const int chunk = q & 7;
    const int r  = (chunk << 4) + (lane >> 2);      // 0..127
    const int gl = (lane & 3) ^ ((r >> 1) & 3);
    const int rowg = ((mat == 0) ? row0 : col0) + r;
    const unsigned short* P = (mat == 0) ? Ah_ : ((mat == 1) ? B1h_ : B2h_);
    gsrc[j]  = P + (size_t)rowg * DIM + (gl << 3);
    ldsoff[j] = (unsigned)(mat * 8192 + chunk * 1024);
  }

  const int fr16 = lane & 15;
  const int kg   = lane >> 4;
  int ra[2], rb[4];
  #pragma unroll
  for (int f = 0; f < 2; ++f) ra[f] = wr + (f << 4) + fr16;
  #pragma unroll
  for (int f = 0; f < 4; ++f) rb[f] = wc + (f << 4) + fr16;

  #define LDFRAGD(bf, mat, r) \
    (*(const h8v*)((const char*)sAB + (bf) * 24576 + (mat) * 8192 + (r) * 64 + (((kg ^ (((r) >> 1) & 3)) << 4))))
  #define STAGED(bf, ko)                                                      \
    {                                                                         \
      _Pragma("unroll")                                                       \
      for (int j = 0; j < 3; ++j)                                             \
        gload16(gsrc[j] + (ko), (char*)sAB + (bf) * 24576 + ldsoff[j]);       \
    }

  int cur = 0;
  STAGED(0, 0);
  __syncthreads();

  for (int kt = 0; kt < DIM / 32; ++kt){
    if (kt < DIM / 32 - 1) STAGED(cur ^ 1, (kt + 1) << 5);

    h8v Ahf[2], Bf[4];
    #pragma unroll
    for (int f = 0; f < 2; ++f) Ahf[f] = LDFRAGD(cur, 0, ra[f]);
    #pragma unroll
    for (int f = 0; f < 4; ++f) Bf[f] = LDFRAGD(cur, 1, rb[f]);
    #pragma unroll
    for (int fi = 0; fi < 2; ++fi)
      #pragma unroll
      for (int fj = 0; fj < 4; ++fj)
        acc1[fi][fj] = __builtin_amdgcn_mfma_f32_16x16x32_f16(Bf[fj], Ahf[fi], acc1[fi][fj], 0, 0, 0);
    #pragma unroll
    for (int f = 0; f < 4; ++f) Bf[f] = LDFRAGD(cur, 2, rb[f]);
    #pragma unroll
    for (int fi = 0; fi < 2; ++fi)
      #pragma unroll
      for (int fj = 0; fj < 4; ++fj)
        acc2[fi][fj] = __builtin_amdgcn_mfma_f32_16x16x32_f16(Bf[fj], Ahf[fi], acc2[fi][fj], 0, 0, 0);

    __syncthreads();
    cur ^= 1;
  }
  #undef LDFRAGD
  #undef STAGED

  const int mloc = lane & 15;
  const int nq   = (lane >> 4) << 2;
  // acts epilogue (fp16 store)
  #pragma unroll
  for (int fi = 0; fi < 2; ++fi){
    const int grow = row0 + wr + (fi << 4) + mloc;
    #pragma unroll
    for (int fj = 0; fj < 4; ++fj){
      const int gcol = col0 + wc + (fj << 4) + nq;
      const float4 be = *(const float4*)(benc + gcol);
      us4v h;
      h[0] = __builtin_bit_cast(unsigned short, (_Float16)fmaxf(acc1[fi][fj][0] + be.x, 0.f));
      h[1] = __builtin_bit_cast(unsigned short, (_Float16)fmaxf(acc1[fi][fj][1] + be.y, 0.f));
      h[2] = __builtin_bit_cast(unsigned short, (_Float16)fmaxf(acc1[fi][fj][2] + be.z, 0.f));
      h[3] = __builtin_bit_cast(unsigned short, (_Float16)fmaxf(acc1[fi][fj][3] + be.w, 0.f));
      __builtin_nontemporal_store(h, (us4v*)(acts16 + (size_t)grow * FEAT + gcol));
    }
  }
  // kest epilogue
  #pragma unroll
  for (int fi = 0; fi < 2; ++fi){
    float ssum = 0.f;
    #pragma unroll
    for (int fj = 0; fj < 4; ++fj){
      const int gcol = col0 + wc + (fj << 4) + nq;
      const float4 be = *(const float4*)(bk1 + gcol);
      const float4 wk = *(const float4*)(w2 + gcol);
      float h0 = fmaxf(acc2[fi][fj][0] + be.x, 0.f);
      float h1 = fmaxf(acc2[fi][fj][1] + be.y, 0.f);
      float h2 = fmaxf(acc2[fi][fj][2] + be.z, 0.f);
      float h3 = fmaxf(acc2[fi][fj][3] + be.w, 0.f);
      ssum = fmaf(h0, wk.x, ssum);
      ssum = fmaf(h1, wk.y, ssum);
      ssum = fmaf(h2, wk.z, ssum);
      ssum = fmaf(h3, wk.w, ssum);
    }
    ssum += __shfl_xor(ssum, 16);
    ssum += __shfl_xor(ssum, 32);
    if (lane < 16){
      const int grow = row0 + wr + (fi << 4) + lane;
      zpart[(size_t)grow * 256 + (bx << 1) + (wc >> 6)] = ssum;
    }
  }
}

// ===========================================================================
// Exact kest GEMM on GATHERED flagged rows (3-product fp32-equivalent).
// ===========================================================================
__global__ __launch_bounds__(512, 4)
void gemmx(const unsigned short* __restrict__ Ah_, const unsigned short* __restrict__ Al_,
           const unsigned short* __restrict__ Bh_, const unsigned short* __restrict__ Bl_,
           const float* __restrict__ bias, const float* __restrict__ w2,
           const int* __restrict__ rowList, const int* __restrict__ nflagp,
           float* __restrict__ zexact)
{
  const int panel = blockIdx.x >> 7;          // 0..15
  const int bx    = blockIdx.x & 127;
  const int row0p = panel << 7;
  if (row0p >= *nflagp) return;
  const int col0 = bx << 7;

  __shared__ unsigned short sAB[2][2][128][64];
  const int tid  = threadIdx.x;
  const int lane = tid & 63, wv = tid >> 6;
  const int wr = (wv & 3) << 5, wc = (wv >> 2) << 6;

  f4v acc[2][4], acc2[2][4];
  #pragma unroll
  for (int i = 0; i < 2; ++i)
    #pragma unroll
    for (int j = 0; j < 4; ++j){
      acc[i][j]  = (f4v){0.f, 0.f, 0.f, 0.f};
      acc2[i][j] = (f4v){0.f, 0.f, 0.f, 0.f};
    }

  const unsigned short* gsrc[4];
  unsigned ldsoff[4];
  #pragma unroll
  for (int j = 0; j < 4; ++j){
    const int q = (wv << 2) + j;
    const int mat = q >> 4;
    const int chunk = q & 15;
    const int r  = (chunk << 3) + (lane >> 3);
    const int gl = (lane & 7) ^ (r & 7);
    const int co = (gl & 3) << 3;
    const unsigned short* hi = (mat == 0) ? Ah_ : Bh_;
    const unsigned short* lo = (mat == 0) ? Al_ : Bl_;
    const int rowg = (mat == 0) ? rowList[row0p + r] : (col0 + r);
    gsrc[j]  = ((gl < 4) ? hi : lo) + (size_t)rowg * DIM + co;
    ldsoff[j] = (unsigned)(mat * 16384 + chunk * 1024);
  }

  const int fr16 = lane & 15;
  const int kg   = lane >> 4;
  int ra[2], rb[4];
  #pragma unroll
  for (int f = 0; f < 2; ++f) ra[f] = wr + (f << 4) + fr16;
  #pragma unroll
  for (int f = 0; f < 4; ++f) rb[f] = wc + (f << 4) + fr16;

  #define LDFRAG(bf, mat, r, hb) \
    (*(const h8v*)((const char*)sAB + (bf) * 32768 + (mat) * 16384 + (r) * 128 + (((((hb) + kg) ^ ((r) & 7)) << 4))))
  #define STAGE(bf, ko)                                                       \
    {                                                                         \
      _Pragma("unroll")                                                       \
      for (int j = 0; j < 4; ++j)                                             \
        gload16(gsrc[j] + (ko), (char*)sAB + (bf) * 32768 + ldsoff[j]);       \
    }

  int cur = 0;
  STAGE(0, 0);
  __syncthreads();

  for (int kt = 0; kt < DIM / 32; ++kt){
    if (kt < DIM / 32 - 1) STAGE(cur ^ 1, (kt + 1) << 5);

    h8v Ahf[2], Bhf[4], Xl[4];
    #pragma unroll
    for (int f = 0; f < 2; ++f) Ahf[f] = LDFRAG(cur, 0, ra[f], 0);
    #pragma unroll
    for (int f = 0; f < 4; ++f) Bhf[f] = LDFRAG(cur, 1, rb[f], 0);
    #pragma unroll
    for (int fi = 0; fi < 2; ++fi)
      #pragma unroll
      for (int fj = 0; fj < 4; ++fj)
        acc[fi][fj] = __builtin_amdgcn_mfma_f32_16x16x32_f16(Bhf[fj], Ahf[fi], acc[fi][fj], 0, 0, 0);
    #pragma unroll
    for (int f = 0; f < 2; ++f) Xl[f] = LDFRAG(cur, 0, ra[f], 4);
    #pragma unroll
    for (int fi = 0; fi < 2; ++fi)
      #pragma unroll
      for (int fj = 0; fj < 4; ++fj)
        acc2[fi][fj] = __builtin_amdgcn_mfma_f32_16x16x32_f16(Bhf[fj], Xl[fi], acc2[fi][fj], 0, 0, 0);
    #pragma unroll
    for (int f = 0; f < 4; ++f) Xl[f] = LDFRAG(cur, 1, rb[f], 4);
    #pragma unroll
    for (int fi = 0; fi < 2; ++fi)
      #pragma unroll
      for (int fj = 0; fj < 4; ++fj)
        acc2[fi][fj] = __builtin_amdgcn_mfma_f32_16x16x32_f16(Xl[fj], Ahf[fi], acc2[fi][fj], 0, 0, 0);

    __syncthreads();
    cur ^= 1;
  }
  #undef LDFRAG
  #undef STAGE

  const float LSC = 1.0f / 2048.0f;
  const int nq = (lane >> 4) << 2;
  #pragma unroll
  for (int fi = 0; fi < 2; ++fi){
    float ssum = 0.f;
    #pragma unroll
    for (int fj = 0; fj < 4; ++fj){
      const int gcol = col0 + wc + (fj << 4) + nq;
      const float4 be = *(const float4*)(bias + gcol);
      const float4 wk = *(const float4*)(w2 + gcol);
      float h0 = fmaxf(acc[fi][fj][0] + LSC * acc2[fi][fj][0] + be.x, 0.f);
      float h1 = fmaxf(acc[fi][fj][1] + LSC * acc2[fi][fj][1] + be.y, 0.f);
      float h2 = fmaxf(acc[fi][fj][2] + LSC * acc2[fi][fj][2] + be.z, 0.f);
      float h3 = fmaxf(acc[fi][fj][3] + LSC * acc2[fi][fj][3] + be.w, 0.f);
      ssum = fmaf(h0, wk.x, ssum);
      ssum = fmaf(h1, wk.y, ssum);
      ssum = fmaf(h2, wk.z, ssum);
      ssum = fmaf(h3, wk.w, ssum);
    }
    ssum += __shfl_xor(ssum, 16);
    ssum += __shfl_xor(ssum, 32);
    if (lane < 16){
      const int pos = row0p + wr + (fi << 4) + lane;
      zexact[(size_t)pos * 256 + (bx << 1) + (wc >> 6)] = ssum;
    }
  }
}

// ===========================================================================
// tail kernels
// ===========================================================================
__global__ __launch_bounds__(256)
void zinit(int* __restrict__ rowList, int* __restrict__ nflag)
{
  const int i = blockIdx.x * 256 + threadIdx.x;
  if (i < MAXF) rowList[i] = 0;
  if (i == 0) *nflag = 0;
}

__global__ __launch_bounds__(256)
void zreduce_flag(const float* __restrict__ zpart, const float* __restrict__ bk2,
                  const int* __restrict__ kp, int* __restrict__ mrow,
                  int* __restrict__ rowList, int* __restrict__ nflag)
{
  const int row  = blockIdx.x * 4 + (threadIdx.x >> 6);
  const int lane = threadIdx.x & 63;
  const float* zp = zpart + (size_t)row * 256;
  float s = zp[lane] + zp[lane + 64] + zp[lane + 128] + zp[lane + 192];
  s += __shfl_xor(s, 1);
  s += __shfl_xor(s, 2);
  s += __shfl_xor(s, 4);
  s += __shfl_xor(s, 8);
  s += __shfl_xor(s, 16);
  s += __shfl_xor(s, 32);
  if (lane == 0){
    float z = s + bk2[0];
    float kest = 2.f * (float)(*kp) * (1.f / (1.f + expf(-z)));
    int m = (int)ceilf(kest);
    m = min(max(m, 0), 128);
    mrow[row] = m;
    const float frac = kest - floorf(kest);
    const float dmin = fminf(frac, 1.f - frac);
    if (dmin < 0.1f){
      int p = atomicAdd(nflag, 1);
      if (p < MAXF) rowList[p] = row;
    }
  }
}

__global__ __launch_bounds__(256)
void zreduce2(const float* __restrict__ zexact, const int* __restrict__ rowList,
              const int* __restrict__ nflagp, const float* __restrict__ bk2,
              const int* __restrict__ kp, int* __restrict__ mrow)
{
  const int pos  = blockIdx.x * 4 + (threadIdx.x >> 6);
  const int lane = threadIdx.x & 63;
  const int nf = min(*nflagp, MAXF);
  if (pos >= nf) return;
  const float* zp = zexact + (size_t)pos * 256;
  float s = zp[lane] + zp[lane + 64] + zp[lane + 128] + zp[lane + 192];
  s += __shfl_xor(s, 1);
  s += __shfl_xor(s, 2);
  s += __shfl_xor(s, 4);
  s += __shfl_xor(s, 8);
  s += __shfl_xor(s, 16);
  s += __shfl_xor(s, 32);
  if (lane == 0){
    float z = s + bk2[0];
    float kest = 2.f * (float)(*kp) * (1.f / (1.f + expf(-z)));
    int m = (int)ceilf(kest);
    m = min(max(m, 0), 128);
    mrow[rowList[pos]] = m;
  }
}

__device__ __forceinline__ void radix_find(int* hist, int nbins, int need, int tid,
                                           int* out3, int* blksum)
{
  const int per  = nbins >> 8;
  const int base = tid * per;
  int bs = 0;
  for (int j = 0; j < per; ++j) bs += hist[base + j];
  blksum[tid] = bs;
  __syncthreads();
  if (tid == 0){
    int a2 = 0;
    for (int t = 255; t >= 0; --t){ int v = blksum[t]; blksum[t] = a2; a2 += v; }
  }
  __syncthreads();
  int ch = blksum[tid];
  for (int j = per - 1; j >= 0; --j){
    const int b = base + j;
    const int c = hist[b];
    if (ch < need && need <= ch + c){ out3[0] = b; out3[1] = need - ch; out3[2] = ch; }
    ch += c;
  }
  __syncthreads();
}

// Band select on fp16 approx acts (proven r13)
__global__ __launch_bounds__(256)
void select_band(const _Float16* __restrict__ acts16, const float* __restrict__ x,
                 const float* __restrict__ bdec, const float* __restrict__ Wenc,
                 const int* __restrict__ mrow, int* __restrict__ selIdx,
                 float* __restrict__ selVal, int* __restrict__ scount)
{
  __shared__ int hist[2048];        // later reused as float xcs[2048]
  __shared__ int blksum[256];
  __shared__ int out3[4];
  __shared__ unsigned short listU[2048];
  __shared__ int listI[2048];
  __shared__ int h32[32];
  __shared__ int lcnt, dcnt, acnt;
  __shared__ unsigned short ambU[64];
  __shared__ int ambI[64];
  __shared__ double ambE[64];
  __shared__ double wred[4];

  const int row = blockIdx.x, tid = threadIdx.x;
  const int m = mrow[row];
  const unsigned short* rp = (const unsigned short*)(acts16 + (size_t)row * FEAT);
  const int base = row << 7;

  for (int i = tid; i < 2048; i += 256) hist[i] = 0;
  __syncthreads();
  // pass 1: hist of u16 >> 5 (8 fp16 per uint4 read)
  for (int it = 0; it < 8; ++it){
    const int i8 = (it << 8) + tid;               // 0..2047
    const uint4 u4 = *(const uint4*)(rp + i8 * 8);
    #pragma unroll
    for (int w = 0; w < 4; ++w){
      const unsigned ww = (&u4.x)[w];
      const unsigned a = ww & 0xFFFFu, b = ww >> 16;
      if (a) atomicAdd(&hist[a >> 5], 1);
      if (b) atomicAdd(&hist[b >> 5], 1);
    }
  }
  __syncthreads();
  radix_find(hist, 2048, m, tid, out3, blksum);
  const int bin1 = out3[0];
  const int rem1 = out3[1];
  const int bin1m1 = (bin1 > 1) ? bin1 - 1 : 1;

  if (tid == 0){ lcnt = 0; dcnt = 0; acnt = 0; }
  if (tid < 32) h32[tid] = 0;
  __syncthreads();
  // pass 2: collect (u16, idx) for bins >= bin1-1
  for (int it = 0; it < 8; ++it){
    const int i8 = (it << 8) + tid;
    const uint4 u4 = *(const uint4*)(rp + i8 * 8);
    const int ib = i8 << 3;
    #pragma unroll
    for (int w = 0; w < 4; ++w){
      const unsigned ww = (&u4.x)[w];
      const unsigned a = ww & 0xFFFFu, b = ww >> 16;
      if ((int)(a >> 5) >= bin1m1){
        int p = atomicAdd(&lcnt, 1);
        if (p < 2048){ listU[p] = (unsigned short)a; listI[p] = ib + 2 * w; }
      }
      if ((int)(b >> 5) >= bin1m1){
        int p = atomicAdd(&lcnt, 1);
        if (p < 2048){ listU[p] = (unsigned short)b; listI[p] = ib + 2 * w + 1; }
      }
    }
  }
  __syncthreads();
  const int L = min(lcnt, 2048);

  // exact vm: rem1-th largest low-5-bit value among bin1 elements
  for (int i = tid; i < L; i += 256){
    const unsigned u = listU[i];
    if ((int)(u >> 5) == bin1) atomicAdd(&h32[u & 31], 1);
  }
  __syncthreads();
  if (tid == 0){
    int c = 0, b3 = 0;
    for (int j = 31; j >= 0; --j){
      c += h32[j];
      if (c >= rem1){ b3 = j; break; }
    }
    out3[3] = b3;
  }
  __syncthreads();
  const unsigned short vm16 = (unsigned short)(((unsigned)bin1 << 5) | (unsigned)out3[3]);
  const float vmf = (float)__builtin_bit_cast(_Float16, vm16);
  const float EPS2 = 0.01f;
  const float lo_cut = vmf - EPS2, hi_cut = vmf + EPS2;

  for (int i = tid; i < L; i += 256){
    const float f = (float)__builtin_bit_cast(_Float16, listU[i]);
    if (f > hi_cut){
      int p = atomicAdd(&dcnt, 1);
      selIdx[base + p] = listI[i];
      selVal[base + p] = f;
    } else if (f >= lo_cut){
      int p = atomicAdd(&acnt, 1);
      if (p < 64){ ambU[p] = listU[i]; ambI[p] = listI[i]; }
    }
  }
  __syncthreads();
  const int D = dcnt;
  const int A = min(acnt, 64);
  int need = m - D;
  if (need < 0) need = 0;
  if (need > A) need = A;

  if (need > 0){
    float* xcs = (float*)hist;
    for (int j = tid; j < DIM; j += 256)
      xcs[j] = x[(size_t)row * DIM + j] - bdec[j];
    __syncthreads();
    const int lane = tid & 63, wv = tid >> 6;
    for (int c = 0; c < A; ++c){
      const float* wrow = Wenc + (size_t)ambI[c] * DIM;
      double sd = 0.0;
      for (int j = tid; j < DIM; j += 256)
        sd += (double)xcs[j] * (double)wrow[j];
      #pragma unroll
      for (int off = 32; off; off >>= 1) sd += __shfl_xor(sd, off);
      if (lane == 0) wred[wv] = sd;
      __syncthreads();
      if (tid == 0) ambE[c] = wred[0] + wred[1] + wred[2] + wred[3];
      __syncthreads();
    }
    if (tid == 0){
      for (int e = 0; e < need; ++e){
        int best = -1;
        for (int c = 0; c < A; ++c){
          if (ambI[c] < 0) continue;
          if (best < 0 || ambE[c] > ambE[best] ||
              (ambE[c] == ambE[best] && ambI[c] < ambI[best])) best = c;
        }
        selIdx[base + D + e] = ambI[best];
        selVal[base + D + e] = (float)__builtin_bit_cast(_Float16, ambU[best]);
        ambI[best] = -1;
      }
    }
  }
  if (tid == 0) scount[row] = D + need;
}

// W_dec [DIM][FEAT] fp32 -> WdT16 [FEAT][DIM] fp16
__global__ __launch_bounds__(256)
void transpose_dec(const float* __restrict__ Wd, _Float16* __restrict__ WdT16)
{
  __shared__ float t[64][65];
  const int f0 = blockIdx.x << 6, d0 = blockIdx.y << 6;
  const int tx = threadIdx.x & 15, ty = threadIdx.x >> 4;
  #pragma unroll
  for (int r = 0; r < 4; ++r){
    const int d = ty + (r << 4);
    const float4 v = *(const float4*)(Wd + (size_t)(d0 + d) * FEAT + f0 + (tx << 2));
    t[d][(tx << 2) + 0] = v.x;
    t[d][(tx << 2) + 1] = v.y;
    t[d][(tx << 2) + 2] = v.z;
    t[d][(tx << 2) + 3] = v.w;
  }
  __syncthreads();
  #pragma unroll
  for (int r = 0; r < 4; ++r){
    const int f = ty + (r << 4);
    ushort4 o;
    o.x = __builtin_bit_cast(unsigned short, (_Float16)t[(tx << 2) + 0][f]);
    o.y = __builtin_bit_cast(unsigned short, (_Float16)t[(tx << 2) + 1][f]);
    o.z = __builtin_bit_cast(unsigned short, (_Float16)t[(tx << 2) + 2][f]);
    o.w = __builtin_bit_cast(unsigned short, (_Float16)t[(tx << 2) + 3][f]);
    *(ushort4*)(WdT16 + (size_t)(f0 + f) * DIM + d0 + (tx << 2)) = o;
  }
}

__global__ __launch_bounds__(256)
void decode_k(const _Float16* __restrict__ WdT16, const int* __restrict__ selIdx,
              const float* __restrict__ selVal, const int* __restrict__ scount,
              const float* __restrict__ bdec, float* __restrict__ out)
{
  __shared__ int   sI[128];
  __shared__ float sV[128];
  const int row = blockIdx.x, tid = threadIdx.x;
  const int m = scount[row];
  if (tid < m){
    sI[tid] = selIdx[(row << 7) + tid];
    sV[tid] = selVal[(row << 7) + tid];
  }
  __syncthreads();
  const int d = tid << 3;
  float a[8];
  {
    const float4 b0 = *(const float4*)(bdec + d);
    const float4 b1 = *(const float4*)(bdec + d + 4);
    a[0] = b0.x; a[1] = b0.y; a[2] = b0.z; a[3] = b0.w;
    a[4] = b1.x; a[5] = b1.y; a[6] = b1.z; a[7] = b1.w;
  }
  for (int i = 0; i < m; ++i){
    const float v = sV[i];
    const h8v w = *(const h8v*)(WdT16 + (size_t)sI[i] * DIM + d);
    #pragma unroll
    for (int j = 0; j < 8; ++j)
      a[j] = fmaf(v, (float)w[j], a[j]);
  }
  float4 o0 = {a[0], a[1], a[2], a[3]};
  float4 o1 = {a[4], a[5], a[6], a[7]};
  *(float4*)(out + (size_t)row * DIM + d)     = o0;
  *(float4*)(out + (size_t)row * DIM + d + 4) = o1;
}

// ===========================================================================
extern "C" void kernel_launch(void* const* d_in, const int* in_sizes, int n_in,
                              void* d_out, int out_size, void* d_ws, size_t ws_size,
                              hipStream_t stream)
{
  const float* x    = (const float*)d_in[0];
  const float* Wenc = (const float*)d_in[1];
  const float* benc = (const float*)d_in[2];
  const float* Wk1  = (const float*)d_in[3];
  const float* bk1  = (const float*)d_in[4];
  const float* Wk2  = (const float*)d_in[5];
  const float* bk2  = (const float*)d_in[6];
  const float* Wdec = (const float*)d_in[7];
  const float* bdec = (const float*)d_in[8];
  const int*   kp   = (const int*)d_in[9];
  float* out = (float*)d_out;

  char* ws = (char*)d_ws;
  const size_t XS_BYTES   = (size_t)BATCH * DIM * 2;      // 16 MB per plane
  const size_t ACTS_BYTES = (size_t)BATCH * FEAT * 4;     // keep 256 MB reservation
  const size_t WP_BYTES   = (size_t)FEAT * DIM * 2;       // 64 MB per plane

  unsigned short* xs0 = (unsigned short*)ws;
  unsigned short* xs1 = (unsigned short*)(ws + XS_BYTES);
  char* p = ws + 2 * XS_BYTES;
  _Float16* acts16 = (_Float16*)p;         // 128 MB used
  _Float16* WdT16  = (_Float16*)p;         // aliased after select (64 MB)
  p += ACTS_BYTES;
  unsigned short* wk0 = (unsigned short*)p;                   // Wk1 hi
  unsigned short* wk1 = (unsigned short*)(p + WP_BYTES);      // Wk1 lo
  unsigned short* we0 = (unsigned short*)(p + 2 * WP_BYTES);  // Wenc hi
  p += 3 * WP_BYTES;
  float* zpart  = (float*)p;               p += 4194304;
  int*   mrow   = (int*)p;                 p += 16384;
  int*   selIdx = (int*)p;                 p += 2097152;
  float* selVal = (float*)p;               p += 2097152;
  int*   scount = (int*)p;                 p += 16384;
  int*   rowList= (int*)p;                 p += MAXF * 4;
  int*   nflag  = (int*)p;                 p += 128;
  float* zexact = (float*)p;               p += (size_t)MAXF * 256 * 4;

  (void)ws_size; (void)in_sizes; (void)n_in; (void)out_size;

  splitX<<<dim3(BATCH * DIM / 1024), dim3(256), 0, stream>>>(x, bdec, xs0, xs1);
  splitW<<<dim3(FEAT * DIM / 1024), dim3(256), 0, stream>>>(Wk1, wk0, wk1);
  splitW1<<<dim3(FEAT * DIM / 1024), dim3(256), 0, stream>>>(Wenc, we0);
  // fused dual GEMM: acts16 (approx) + kest zpart (approx)
  gemmd<<<dim3(4096), dim3(512), 0, stream>>>(xs0, we0, wk0, benc, bk1, Wk2,
                                              acts16, zpart);
  zinit<<<dim3(MAXF / 256), dim3(256), 0, stream>>>(rowList, nflag);
  zreduce_flag<<<dim3(BATCH / 4), dim3(256), 0, stream>>>(zpart, bk2, kp, mrow,
                                                          rowList, nflag);
  // exact recompute of flagged rows only
  gemmx<<<dim3(16 * 128), dim3(512), 0, stream>>>(xs0, xs1, wk0, wk1, bk1, Wk2,
                                                  rowList, nflag, zexact);
  zreduce2<<<dim3(MAXF / 4), dim3(256), 0, stream>>>(zexact, rowList, nflag,
                                                     bk2, kp, mrow);
  select_band<<<dim3(BATCH), dim3(256), 0, stream>>>(acts16, x, bdec, Wenc, mrow,
                                                     selIdx, selVal, scount);
  transpose_dec<<<dim3(FEAT / 64, DIM / 64), dim3(256), 0, stream>>>(Wdec, WdT16);
  decode_k<<<dim3(BATCH), dim3(256), 0, stream>>>(WdT16, selIdx, selVal, scount, bdec, out);
}

// Round 15
// 1119.183 us; speedup vs baseline: 1.0073x; 1.0073x over previous
//
#include <hip/hip_runtime.h>
#include <hip/hip_bf16.h>
#include <cstdint>
#include <cstddef>

#define BATCH 4096
#define DIM   2048
#define FEAT  16384
#define MAXF  2048          // cap on flagged rows for exact kest recompute

typedef __attribute__((ext_vector_type(8))) _Float16 h8v;
typedef __attribute__((ext_vector_type(4))) float f4v;
typedef __attribute__((ext_vector_type(4))) unsigned short us4v;

__device__ __forceinline__ void split2(float v, unsigned short &h, unsigned short &l){
  _Float16 hf = (_Float16)v;
  _Float16 lf = (_Float16)((v - (float)hf) * 2048.0f);
  h = __builtin_bit_cast(unsigned short, hf);
  l = __builtin_bit_cast(unsigned short, lf);
}

__device__ __forceinline__ void gload16(const void* g, void* l){
  __builtin_amdgcn_global_load_lds(
      (const __attribute__((address_space(1))) void*)g,
      (__attribute__((address_space(3))) void*)l, 16, 0, 0);
}

// ===========================================================================
// split kernels
// ===========================================================================
__global__ __launch_bounds__(256)
void splitX(const float* __restrict__ x, const float* __restrict__ bdec,
            unsigned short* __restrict__ p0, unsigned short* __restrict__ p1)
{
  const size_t i = ((size_t)blockIdx.x * 256 + threadIdx.x) * 4;
  const int col = (int)(i & (DIM - 1));
  const float4 v = *(const float4*)(x + i);
  const float4 b = *(const float4*)(bdec + col);
  float e0 = v.x - b.x, e1 = v.y - b.y, e2 = v.z - b.z, e3 = v.w - b.w;
  ushort4 H, L;
  split2(e0, H.x, L.x); split2(e1, H.y, L.y);
  split2(e2, H.z, L.z); split2(e3, H.w, L.w);
  *(ushort4*)(p0 + i) = H; *(ushort4*)(p1 + i) = L;
}

// fused weight split: y=0 -> Wk1 (hi+lo), y=1 -> Wenc (hi only)
__global__ __launch_bounds__(256)
void splitWs(const float* __restrict__ wk1src, const float* __restrict__ wencsrc,
             unsigned short* __restrict__ wk0, unsigned short* __restrict__ wk1lo,
             unsigned short* __restrict__ we0)
{
  const size_t i = ((size_t)blockIdx.x * 256 + threadIdx.x) * 4;
  if (blockIdx.y == 0){
    const float4 v = *(const float4*)(wk1src + i);
    ushort4 H, L;
    split2(v.x, H.x, L.x); split2(v.y, H.y, L.y);
    split2(v.z, H.z, L.z); split2(v.w, H.w, L.w);
    *(ushort4*)(wk0 + i) = H; *(ushort4*)(wk1lo + i) = L;
  } else {
    const float4 v = *(const float4*)(wencsrc + i);
    ushort4 H;
    H.x = __builtin_bit_cast(unsigned short, (_Float16)v.x);
    H.y = __builtin_bit_cast(unsigned short, (_Float16)v.y);
    H.z = __builtin_bit_cast(unsigned short, (_Float16)v.z);
    H.w = __builtin_bit_cast(unsigned short, (_Float16)v.w);
    *(ushort4*)(we0 + i) = H;
  }
}

// ===========================================================================
// Fused dual 1-product GEMM, r11-proven role-split structure:
// 512 threads / 8 waves; waves 0-3: acts (C1=A*B1^T), waves 4-7: kest
// (C2=A*B2^T). Wave tile 64x64, 8 frags -> 16 MFMA (0.5 KB/MFMA, best
// measured ratio at 45% occupancy). 48 KB LDS dbuf, staging = 24 x 1KB
// chunks (3/wave). acts stored fp16 (band-select tolerant).
// ===========================================================================
__global__ __launch_bounds__(512, 3)
void gemmd(const unsigned short* __restrict__ Ah_, const unsigned short* __restrict__ B1h_,
           const unsigned short* __restrict__ B2h_,
           const float* __restrict__ benc, const float* __restrict__ bk1,
           const float* __restrict__ w2,
           _Float16* __restrict__ acts16, float* __restrict__ zpart)
{
  __shared__ unsigned short sAB[2][3][128][32];   // 48 KB: [buf][A|B1|B2]
  const int tid  = threadIdx.x;
  const int lane = tid & 63, wv = tid >> 6;       // wv 0..7

  const int bid = blockIdx.x;
  const int xcd = bid & 7;
  const int idx = bid >> 3;
  const int sq  = idx >> 6;
  const int s   = idx & 63;
  const int bx  = (xcd << 4) | ((sq & 1) << 3) | (s & 7);
  const int by  = ((sq >> 1) << 3) | (s >> 3);
  const int row0 = by << 7, col0 = bx << 7;

  const int role = wv >> 2;                 // 0: acts, 1: kest
  const int wloc = wv & 3;
  const int wr = (wloc & 1) << 6, wc = (wloc >> 1) << 6;

  f4v acc[4][4];
  #pragma unroll
  for (int i = 0; i < 4; ++i)
    #pragma unroll
    for (int j = 0; j < 4; ++j)
      acc[i][j] = (f4v){0.f, 0.f, 0.f, 0.f};

  // staging: 24 chunks of 1 KB (8 A + 8 B1 + 8 B2); 3 per wave
  const unsigned short* gsrc[3];
  unsigned ldsoff[3];
  #pragma unroll
  for (int j = 0; j < 3; ++j){
    const int q = wv * 3 + j;          // 0..23
    const int mat = q >> 3;            // 0=A, 1=B1, 2=B2
    const int chunk = q & 7;
    const int r  = (chunk << 4) + (lane >> 2);      // 0..127
    const int gl = (lane & 3) ^ ((r >> 1) & 3);
    const int rowg = ((mat == 0) ? row0 : col0) + r;
    const unsigned short* P = (mat == 0) ? Ah_ : ((mat == 1) ? B1h_ : B2h_);
    gsrc[j]  = P + (size_t)rowg * DIM + (gl << 3);
    ldsoff[j] = (unsigned)(mat * 8192 + chunk * 1024);
  }

  const int fr16 = lane & 15;
  const int kg   = lane >> 4;
  const int bmat = 1 + role;
  int ra[4], rb[4];
  #pragma unroll
  for (int f = 0; f < 4; ++f){ ra[f] = wr + (f << 4) + fr16; rb[f] = wc + (f << 4) + fr16; }

  #define LDFRAGD(bf, mat, r) \
    (*(const h8v*)((const char*)sAB + (bf) * 24576 + (mat) * 8192 + (r) * 64 + (((kg ^ (((r) >> 1) & 3)) << 4))))
  #define STAGED(bf, ko)                                                      \
    {                                                                         \
      _Pragma("unroll")                                                       \
      for (int j = 0; j < 3; ++j)                                             \
        gload16(gsrc[j] + (ko), (char*)sAB + (bf) * 24576 + ldsoff[j]);       \
    }

  int cur = 0;
  STAGED(0, 0);
  __syncthreads();

  for (int kt = 0; kt < DIM / 32; ++kt){
    if (kt < DIM / 32 - 1) STAGED(cur ^ 1, (kt + 1) << 5);

    h8v Ahf[4], Bhf[4];
    #pragma unroll
    for (int f = 0; f < 4; ++f) Ahf[f] = LDFRAGD(cur, 0, ra[f]);
    #pragma unroll
    for (int f = 0; f < 4; ++f) Bhf[f] = LDFRAGD(cur, bmat, rb[f]);
    #pragma unroll
    for (int fi = 0; fi < 4; ++fi)
      #pragma unroll
      for (int fj = 0; fj < 4; ++fj)
        acc[fi][fj] = __builtin_amdgcn_mfma_f32_16x16x32_f16(Bhf[fj], Ahf[fi], acc[fi][fj], 0, 0, 0);

    __syncthreads();
    cur ^= 1;
  }
  #undef LDFRAGD
  #undef STAGED

  const int mloc = lane & 15;
  const int nq   = (lane >> 4) << 2;
  if (role == 0){
    // acts epilogue (fp16 store)
    #pragma unroll
    for (int fi = 0; fi < 4; ++fi){
      const int grow = row0 + wr + (fi << 4) + mloc;
      #pragma unroll
      for (int fj = 0; fj < 4; ++fj){
        const int gcol = col0 + wc + (fj << 4) + nq;
        const float4 be = *(const float4*)(benc + gcol);
        us4v h;
        h[0] = __builtin_bit_cast(unsigned short, (_Float16)fmaxf(acc[fi][fj][0] + be.x, 0.f));
        h[1] = __builtin_bit_cast(unsigned short, (_Float16)fmaxf(acc[fi][fj][1] + be.y, 0.f));
        h[2] = __builtin_bit_cast(unsigned short, (_Float16)fmaxf(acc[fi][fj][2] + be.z, 0.f));
        h[3] = __builtin_bit_cast(unsigned short, (_Float16)fmaxf(acc[fi][fj][3] + be.w, 0.f));
        __builtin_nontemporal_store(h, (us4v*)(acts16 + (size_t)grow * FEAT + gcol));
      }
    }
  } else {
    // kest epilogue
    #pragma unroll
    for (int fi = 0; fi < 4; ++fi){
      float ssum = 0.f;
      #pragma unroll
      for (int fj = 0; fj < 4; ++fj){
        const int gcol = col0 + wc + (fj << 4) + nq;
        const float4 be = *(const float4*)(bk1 + gcol);
        const float4 wk = *(const float4*)(w2 + gcol);
        float h0 = fmaxf(acc[fi][fj][0] + be.x, 0.f);
        float h1 = fmaxf(acc[fi][fj][1] + be.y, 0.f);
        float h2 = fmaxf(acc[fi][fj][2] + be.z, 0.f);
        float h3 = fmaxf(acc[fi][fj][3] + be.w, 0.f);
        ssum = fmaf(h0, wk.x, ssum);
        ssum = fmaf(h1, wk.y, ssum);
        ssum = fmaf(h2, wk.z, ssum);
        ssum = fmaf(h3, wk.w, ssum);
      }
      ssum += __shfl_xor(ssum, 16);
      ssum += __shfl_xor(ssum, 32);
      if (lane < 16){
        const int grow = row0 + wr + (fi << 4) + lane;
        zpart[(size_t)grow * 256 + (bx << 1) + (wc >> 6)] = ssum;
      }
    }
  }
}

// ===========================================================================
// Exact kest GEMM on GATHERED flagged rows (3-product fp32-equivalent).
// ===========================================================================
__global__ __launch_bounds__(512, 4)
void gemmx(const unsigned short* __restrict__ Ah_, const unsigned short* __restrict__ Al_,
           const unsigned short* __restrict__ Bh_, const unsigned short* __restrict__ Bl_,
           const float* __restrict__ bias, const float* __restrict__ w2,
           const int* __restrict__ rowList, const int* __restrict__ nflagp,
           float* __restrict__ zexact)
{
  const int panel = blockIdx.x >> 7;          // 0..15
  const int bx    = blockIdx.x & 127;
  const int row0p = panel << 7;
  if (row0p >= *nflagp) return;
  const int col0 = bx << 7;

  __shared__ unsigned short sAB[2][2][128][64];
  const int tid  = threadIdx.x;
  const int lane = tid & 63, wv = tid >> 6;
  const int wr = (wv & 3) << 5, wc = (wv >> 2) << 6;

  f4v acc[2][4], acc2[2][4];
  #pragma unroll
  for (int i = 0; i < 2; ++i)
    #pragma unroll
    for (int j = 0; j < 4; ++j){
      acc[i][j]  = (f4v){0.f, 0.f, 0.f, 0.f};
      acc2[i][j] = (f4v){0.f, 0.f, 0.f, 0.f};
    }

  const unsigned short* gsrc[4];
  unsigned ldsoff[4];
  #pragma unroll
  for (int j = 0; j < 4; ++j){
    const int q = (wv << 2) + j;
    const int mat = q >> 4;
    const int chunk = q & 15;
    const int r  = (chunk << 3) + (lane >> 3);
    const int gl = (lane & 7) ^ (r & 7);
    const int co = (gl & 3) << 3;
    const unsigned short* hi = (mat == 0) ? Ah_ : Bh_;
    const unsigned short* lo = (mat == 0) ? Al_ : Bl_;
    const int rowg = (mat == 0) ? rowList[row0p + r] : (col0 + r);
    gsrc[j]  = ((gl < 4) ? hi : lo) + (size_t)rowg * DIM + co;
    ldsoff[j] = (unsigned)(mat * 16384 + chunk * 1024);
  }

  const int fr16 = lane & 15;
  const int kg   = lane >> 4;
  int ra[2], rb[4];
  #pragma unroll
  for (int f = 0; f < 2; ++f) ra[f] = wr + (f << 4) + fr16;
  #pragma unroll
  for (int f = 0; f < 4; ++f) rb[f] = wc + (f << 4) + fr16;

  #define LDFRAG(bf, mat, r, hb) \
    (*(const h8v*)((const char*)sAB + (bf) * 32768 + (mat) * 16384 + (r) * 128 + (((((hb) + kg) ^ ((r) & 7)) << 4))))
  #define STAGE(bf, ko)                                                       \
    {                                                                         \
      _Pragma("unroll")                                                       \
      for (int j = 0; j < 4; ++j)                                             \
        gload16(gsrc[j] + (ko), (char*)sAB + (bf) * 32768 + ldsoff[j]);       \
    }

  int cur = 0;
  STAGE(0, 0);
  __syncthreads();

  for (int kt = 0; kt < DIM / 32; ++kt){
    if (kt < DIM / 32 - 1) STAGE(cur ^ 1, (kt + 1) << 5);

    h8v Ahf[2], Bhf[4], Xl[4];
    #pragma unroll
    for (int f = 0; f < 2; ++f) Ahf[f] = LDFRAG(cur, 0, ra[f], 0);
    #pragma unroll
    for (int f = 0; f < 4; ++f) Bhf[f] = LDFRAG(cur, 1, rb[f], 0);
    #pragma unroll
    for (int fi = 0; fi < 2; ++fi)
      #pragma unroll
      for (int fj = 0; fj < 4; ++fj)
        acc[fi][fj] = __builtin_amdgcn_mfma_f32_16x16x32_f16(Bhf[fj], Ahf[fi], acc[fi][fj], 0, 0, 0);
    #pragma unroll
    for (int f = 0; f < 2; ++f) Xl[f] = LDFRAG(cur, 0, ra[f], 4);
    #pragma unroll
    for (int fi = 0; fi < 2; ++fi)
      #pragma unroll
      for (int fj = 0; fj < 4; ++fj)
        acc2[fi][fj] = __builtin_amdgcn_mfma_f32_16x16x32_f16(Bhf[fj], Xl[fi], acc2[fi][fj], 0, 0, 0);
    #pragma unroll
    for (int f = 0; f < 4; ++f) Xl[f] = LDFRAG(cur, 1, rb[f], 4);
    #pragma unroll
    for (int fi = 0; fi < 2; ++fi)
      #pragma unroll
      for (int fj = 0; fj < 4; ++fj)
        acc2[fi][fj] = __builtin_amdgcn_mfma_f32_16x16x32_f16(Xl[fj], Ahf[fi], acc2[fi][fj], 0, 0, 0);

    __syncthreads();
    cur ^= 1;
  }
  #undef LDFRAG
  #undef STAGE

  const float LSC = 1.0f / 2048.0f;
  const int nq = (lane >> 4) << 2;
  #pragma unroll
  for (int fi = 0; fi < 2; ++fi){
    float ssum = 0.f;
    #pragma unroll
    for (int fj = 0; fj < 4; ++fj){
      const int gcol = col0 + wc + (fj << 4) + nq;
      const float4 be = *(const float4*)(bias + gcol);
      const float4 wk = *(const float4*)(w2 + gcol);
      float h0 = fmaxf(acc[fi][fj][0] + LSC * acc2[fi][fj][0] + be.x, 0.f);
      float h1 = fmaxf(acc[fi][fj][1] + LSC * acc2[fi][fj][1] + be.y, 0.f);
      float h2 = fmaxf(acc[fi][fj][2] + LSC * acc2[fi][fj][2] + be.z, 0.f);
      float h3 = fmaxf(acc[fi][fj][3] + LSC * acc2[fi][fj][3] + be.w, 0.f);
      ssum = fmaf(h0, wk.x, ssum);
      ssum = fmaf(h1, wk.y, ssum);
      ssum = fmaf(h2, wk.z, ssum);
      ssum = fmaf(h3, wk.w, ssum);
    }
    ssum += __shfl_xor(ssum, 16);
    ssum += __shfl_xor(ssum, 32);
    if (lane < 16){
      const int pos = row0p + wr + (fi << 4) + lane;
      zexact[(size_t)pos * 256 + (bx << 1) + (wc >> 6)] = ssum;
    }
  }
}

// ===========================================================================
// tail kernels
// ===========================================================================
__global__ __launch_bounds__(256)
void zinit(int* __restrict__ rowList, int* __restrict__ nflag)
{
  const int i = blockIdx.x * 256 + threadIdx.x;
  if (i < MAXF) rowList[i] = 0;
  if (i == 0) *nflag = 0;
}

__global__ __launch_bounds__(256)
void zreduce_flag(const float* __restrict__ zpart, const float* __restrict__ bk2,
                  const int* __restrict__ kp, int* __restrict__ mrow,
                  int* __restrict__ rowList, int* __restrict__ nflag)
{
  const int row  = blockIdx.x * 4 + (threadIdx.x >> 6);
  const int lane = threadIdx.x & 63;
  const float* zp = zpart + (size_t)row * 256;
  float s = zp[lane] + zp[lane + 64] + zp[lane + 128] + zp[lane + 192];
  s += __shfl_xor(s, 1);
  s += __shfl_xor(s, 2);
  s += __shfl_xor(s, 4);
  s += __shfl_xor(s, 8);
  s += __shfl_xor(s, 16);
  s += __shfl_xor(s, 32);
  if (lane == 0){
    float z = s + bk2[0];
    float kest = 2.f * (float)(*kp) * (1.f / (1.f + expf(-z)));
    int m = (int)ceilf(kest);
    m = min(max(m, 0), 128);
    mrow[row] = m;
    const float frac = kest - floorf(kest);
    const float dmin = fminf(frac, 1.f - frac);
    if (dmin < 0.1f){
      int p = atomicAdd(nflag, 1);
      if (p < MAXF) rowList[p] = row;
    }
  }
}

__global__ __launch_bounds__(256)
void zreduce2(const float* __restrict__ zexact, const int* __restrict__ rowList,
              const int* __restrict__ nflagp, const float* __restrict__ bk2,
              const int* __restrict__ kp, int* __restrict__ mrow)
{
  const int pos  = blockIdx.x * 4 + (threadIdx.x >> 6);
  const int lane = threadIdx.x & 63;
  const int nf = min(*nflagp, MAXF);
  if (pos >= nf) return;
  const float* zp = zexact + (size_t)pos * 256;
  float s = zp[lane] + zp[lane + 64] + zp[lane + 128] + zp[lane + 192];
  s += __shfl_xor(s, 1);
  s += __shfl_xor(s, 2);
  s += __shfl_xor(s, 4);
  s += __shfl_xor(s, 8);
  s += __shfl_xor(s, 16);
  s += __shfl_xor(s, 32);
  if (lane == 0){
    float z = s + bk2[0];
    float kest = 2.f * (float)(*kp) * (1.f / (1.f + expf(-z)));
    int m = (int)ceilf(kest);
    m = min(max(m, 0), 128);
    mrow[rowList[pos]] = m;
  }
}

__device__ __forceinline__ void radix_find(int* hist, int nbins, int need, int tid,
                                           int* out3, int* blksum)
{
  const int per  = nbins >> 8;
  const int base = tid * per;
  int bs = 0;
  for (int j = 0; j < per; ++j) bs += hist[base + j];
  blksum[tid] = bs;
  __syncthreads();
  if (tid == 0){
    int a2 = 0;
    for (int t = 255; t >= 0; --t){ int v = blksum[t]; blksum[t] = a2; a2 += v; }
  }
  __syncthreads();
  int ch = blksum[tid];
  for (int j = per - 1; j >= 0; --j){
    const int b = base + j;
    const int c = hist[b];
    if (ch < need && need <= ch + c){ out3[0] = b; out3[1] = need - ch; out3[2] = ch; }
    ch += c;
  }
  __syncthreads();
}

// Band select on fp16 approx acts (proven r13/r14)
__global__ __launch_bounds__(256)
void select_band(const _Float16* __restrict__ acts16, const float* __restrict__ x,
                 const float* __restrict__ bdec, const float* __restrict__ Wenc,
                 const int* __restrict__ mrow, int* __restrict__ selIdx,
                 float* __restrict__ selVal, int* __restrict__ scount)
{
  __shared__ int hist[2048];        // later reused as float xcs[2048]
  __shared__ int blksum[256];
  __shared__ int out3[4];
  __shared__ unsigned short listU[2048];
  __shared__ int listI[2048];
  __shared__ int h32[32];
  __shared__ int lcnt, dcnt, acnt;
  __shared__ unsigned short ambU[64];
  __shared__ int ambI[64];
  __shared__ double ambE[64];
  __shared__ double wred[4];

  const int row = blockIdx.x, tid = threadIdx.x;
  const int m = mrow[row];
  const unsigned short* rp = (const unsigned short*)(acts16 + (size_t)row * FEAT);
  const int base = row << 7;

  for (int i = tid; i < 2048; i += 256) hist[i] = 0;
  __syncthreads();
  // pass 1: hist of u16 >> 5 (8 fp16 per uint4 read)
  for (int it = 0; it < 8; ++it){
    const int i8 = (it << 8) + tid;               // 0..2047
    const uint4 u4 = *(const uint4*)(rp + i8 * 8);
    #pragma unroll
    for (int w = 0; w < 4; ++w){
      const unsigned ww = (&u4.x)[w];
      const unsigned a = ww & 0xFFFFu, b = ww >> 16;
      if (a) atomicAdd(&hist[a >> 5], 1);
      if (b) atomicAdd(&hist[b >> 5], 1);
    }
  }
  __syncthreads();
  radix_find(hist, 2048, m, tid, out3, blksum);
  const int bin1 = out3[0];
  const int rem1 = out3[1];
  const int bin1m1 = (bin1 > 1) ? bin1 - 1 : 1;

  if (tid == 0){ lcnt = 0; dcnt = 0; acnt = 0; }
  if (tid < 32) h32[tid] = 0;
  __syncthreads();
  // pass 2: collect (u16, idx) for bins >= bin1-1
  for (int it = 0; it < 8; ++it){
    const int i8 = (it << 8) + tid;
    const uint4 u4 = *(const uint4*)(rp + i8 * 8);
    const int ib = i8 << 3;
    #pragma unroll
    for (int w = 0; w < 4; ++w){
      const unsigned ww = (&u4.x)[w];
      const unsigned a = ww & 0xFFFFu, b = ww >> 16;
      if ((int)(a >> 5) >= bin1m1){
        int p = atomicAdd(&lcnt, 1);
        if (p < 2048){ listU[p] = (unsigned short)a; listI[p] = ib + 2 * w; }
      }
      if ((int)(b >> 5) >= bin1m1){
        int p = atomicAdd(&lcnt, 1);
        if (p < 2048){ listU[p] = (unsigned short)b; listI[p] = ib + 2 * w + 1; }
      }
    }
  }
  __syncthreads();
  const int L = min(lcnt, 2048);

  // exact vm: rem1-th largest low-5-bit value among bin1 elements
  for (int i = tid; i < L; i += 256){
    const unsigned u = listU[i];
    if ((int)(u >> 5) == bin1) atomicAdd(&h32[u & 31], 1);
  }
  __syncthreads();
  if (tid == 0){
    int c = 0, b3 = 0;
    for (int j = 31; j >= 0; --j){
      c += h32[j];
      if (c >= rem1){ b3 = j; break; }
    }
    out3[3] = b3;
  }
  __syncthreads();
  const unsigned short vm16 = (unsigned short)(((unsigned)bin1 << 5) | (unsigned)out3[3]);
  const float vmf = (float)__builtin_bit_cast(_Float16, vm16);
  const float EPS2 = 0.01f;
  const float lo_cut = vmf - EPS2, hi_cut = vmf + EPS2;

  for (int i = tid; i < L; i += 256){
    const float f = (float)__builtin_bit_cast(_Float16, listU[i]);
    if (f > hi_cut){
      int p = atomicAdd(&dcnt, 1);
      selIdx[base + p] = listI[i];
      selVal[base + p] = f;
    } else if (f >= lo_cut){
      int p = atomicAdd(&acnt, 1);
      if (p < 64){ ambU[p] = listU[i]; ambI[p] = listI[i]; }
    }
  }
  __syncthreads();
  const int D = dcnt;
  const int A = min(acnt, 64);
  int need = m - D;
  if (need < 0) need = 0;
  if (need > A) need = A;

  if (need > 0){
    float* xcs = (float*)hist;
    for (int j = tid; j < DIM; j += 256)
      xcs[j] = x[(size_t)row * DIM + j] - bdec[j];
    __syncthreads();
    const int lane = tid & 63, wv = tid >> 6;
    for (int c = 0; c < A; ++c){
      const float* wrow = Wenc + (size_t)ambI[c] * DIM;
      double sd = 0.0;
      for (int j = tid; j < DIM; j += 256)
        sd += (double)xcs[j] * (double)wrow[j];
      #pragma unroll
      for (int off = 32; off; off >>= 1) sd += __shfl_xor(sd, off);
      if (lane == 0) wred[wv] = sd;
      __syncthreads();
      if (tid == 0) ambE[c] = wred[0] + wred[1] + wred[2] + wred[3];
      __syncthreads();
    }
    if (tid == 0){
      for (int e = 0; e < need; ++e){
        int best = -1;
        for (int c = 0; c < A; ++c){
          if (ambI[c] < 0) continue;
          if (best < 0 || ambE[c] > ambE[best] ||
              (ambE[c] == ambE[best] && ambI[c] < ambI[best])) best = c;
        }
        selIdx[base + D + e] = ambI[best];
        selVal[base + D + e] = (float)__builtin_bit_cast(_Float16, ambU[best]);
        ambI[best] = -1;
      }
    }
  }
  if (tid == 0) scount[row] = D + need;
}

// W_dec [DIM][FEAT] fp32 -> WdT16 [FEAT][DIM] fp16
__global__ __launch_bounds__(256)
void transpose_dec(const float* __restrict__ Wd, _Float16* __restrict__ WdT16)
{
  __shared__ float t[64][65];
  const int f0 = blockIdx.x << 6, d0 = blockIdx.y << 6;
  const int tx = threadIdx.x & 15, ty = threadIdx.x >> 4;
  #pragma unroll
  for (int r = 0; r < 4; ++r){
    const int d = ty + (r << 4);
    const float4 v = *(const float4*)(Wd + (size_t)(d0 + d) * FEAT + f0 + (tx << 2));
    t[d][(tx << 2) + 0] = v.x;
    t[d][(tx << 2) + 1] = v.y;
    t[d][(tx << 2) + 2] = v.z;
    t[d][(tx << 2) + 3] = v.w;
  }
  __syncthreads();
  #pragma unroll
  for (int r = 0; r < 4; ++r){
    const int f = ty + (r << 4);
    ushort4 o;
    o.x = __builtin_bit_cast(unsigned short, (_Float16)t[(tx << 2) + 0][f]);
    o.y = __builtin_bit_cast(unsigned short, (_Float16)t[(tx << 2) + 1][f]);
    o.z = __builtin_bit_cast(unsigned short, (_Float16)t[(tx << 2) + 2][f]);
    o.w = __builtin_bit_cast(unsigned short, (_Float16)t[(tx << 2) + 3][f]);
    *(ushort4*)(WdT16 + (size_t)(f0 + f) * DIM + d0 + (tx << 2)) = o;
  }
}

__global__ __launch_bounds__(256)
void decode_k(const _Float16* __restrict__ WdT16, const int* __restrict__ selIdx,
              const float* __restrict__ selVal, const int* __restrict__ scount,
              const float* __restrict__ bdec, float* __restrict__ out)
{
  __shared__ int   sI[128];
  __shared__ float sV[128];
  const int row = blockIdx.x, tid = threadIdx.x;
  const int m = scount[row];
  if (tid < m){
    sI[tid] = selIdx[(row << 7) + tid];
    sV[tid] = selVal[(row << 7) + tid];
  }
  __syncthreads();
  const int d = tid << 3;
  float a[8];
  {
    const float4 b0 = *(const float4*)(bdec + d);
    const float4 b1 = *(const float4*)(bdec + d + 4);
    a[0] = b0.x; a[1] = b0.y; a[2] = b0.z; a[3] = b0.w;
    a[4] = b1.x; a[5] = b1.y; a[6] = b1.z; a[7] = b1.w;
  }
  for (int i = 0; i < m; ++i){
    const float v = sV[i];
    const h8v w = *(const h8v*)(WdT16 + (size_t)sI[i] * DIM + d);
    #pragma unroll
    for (int j = 0; j < 8; ++j)
      a[j] = fmaf(v, (float)w[j], a[j]);
  }
  float4 o0 = {a[0], a[1], a[2], a[3]};
  float4 o1 = {a[4], a[5], a[6], a[7]};
  *(float4*)(out + (size_t)row * DIM + d)     = o0;
  *(float4*)(out + (size_t)row * DIM + d + 4) = o1;
}

// ===========================================================================
extern "C" void kernel_launch(void* const* d_in, const int* in_sizes, int n_in,
                              void* d_out, int out_size, void* d_ws, size_t ws_size,
                              hipStream_t stream)
{
  const float* x    = (const float*)d_in[0];
  const float* Wenc = (const float*)d_in[1];
  const float* benc = (const float*)d_in[2];
  const float* Wk1  = (const float*)d_in[3];
  const float* bk1  = (const float*)d_in[4];
  const float* Wk2  = (const float*)d_in[5];
  const float* bk2  = (const float*)d_in[6];
  const float* Wdec = (const float*)d_in[7];
  const float* bdec = (const float*)d_in[8];
  const int*   kp   = (const int*)d_in[9];
  float* out = (float*)d_out;

  char* ws = (char*)d_ws;
  const size_t XS_BYTES   = (size_t)BATCH * DIM * 2;      // 16 MB per plane
  const size_t ACTS_BYTES = (size_t)BATCH * FEAT * 4;     // keep 256 MB reservation
  const size_t WP_BYTES   = (size_t)FEAT * DIM * 2;       // 64 MB per plane

  unsigned short* xs0 = (unsigned short*)ws;
  unsigned short* xs1 = (unsigned short*)(ws + XS_BYTES);
  char* p = ws + 2 * XS_BYTES;
  _Float16* acts16 = (_Float16*)p;         // 128 MB used
  _Float16* WdT16  = (_Float16*)p;         // aliased after select (64 MB)
  p += ACTS_BYTES;
  unsigned short* wk0 = (unsigned short*)p;                   // Wk1 hi
  unsigned short* wk1 = (unsigned short*)(p + WP_BYTES);      // Wk1 lo
  unsigned short* we0 = (unsigned short*)(p + 2 * WP_BYTES);  // Wenc hi
  p += 3 * WP_BYTES;
  float* zpart  = (float*)p;               p += 4194304;
  int*   mrow   = (int*)p;                 p += 16384;
  int*   selIdx = (int*)p;                 p += 2097152;
  float* selVal = (float*)p;               p += 2097152;
  int*   scount = (int*)p;                 p += 16384;
  int*   rowList= (int*)p;                 p += MAXF * 4;
  int*   nflag  = (int*)p;                 p += 128;
  float* zexact = (float*)p;               p += (size_t)MAXF * 256 * 4;

  (void)ws_size; (void)in_sizes; (void)n_in; (void)out_size;

  zinit<<<dim3(MAXF / 256), dim3(256), 0, stream>>>(rowList, nflag);
  splitX<<<dim3(BATCH * DIM / 1024), dim3(256), 0, stream>>>(x, bdec, xs0, xs1);
  splitWs<<<dim3(FEAT * DIM / 1024, 2), dim3(256), 0, stream>>>(Wk1, Wenc, wk0, wk1, we0);
  // fused dual GEMM: acts16 (approx) + kest zpart (approx)
  gemmd<<<dim3(4096), dim3(512), 0, stream>>>(xs0, we0, wk0, benc, bk1, Wk2,
                                              acts16, zpart);
  zreduce_flag<<<dim3(BATCH / 4), dim3(256), 0, stream>>>(zpart, bk2, kp, mrow,
                                                          rowList, nflag);
  // exact recompute of flagged rows only
  gemmx<<<dim3(16 * 128), dim3(512), 0, stream>>>(xs0, xs1, wk0, wk1, bk1, Wk2,
                                                  rowList, nflag, zexact);
  zreduce2<<<dim3(MAXF / 4), dim3(256), 0, stream>>>(zexact, rowList, nflag,
                                                     bk2, kp, mrow);
  select_band<<<dim3(BATCH), dim3(256), 0, stream>>>(acts16, x, bdec, Wenc, mrow,
                                                     selIdx, selVal, scount);
  transpose_dec<<<dim3(FEAT / 64, DIM / 64), dim3(256), 0, stream>>>(Wdec, WdT16);
  decode_k<<<dim3(BATCH), dim3(256), 0, stream>>>(WdT16, selIdx, selVal, scount, bdec, out);
}

// Round 17
// 1117.875 us; speedup vs baseline: 1.0085x; 1.0012x over previous
//
#include <hip/hip_runtime.h>
#include <hip/hip_bf16.h>
#include <cstdint>
#include <cstddef>

#define BATCH 4096
#define DIM   2048
#define FEAT  16384
#define MAXF  2048          // cap on flagged rows for exact kest recompute

typedef __attribute__((ext_vector_type(8))) _Float16 h8v;
typedef __attribute__((ext_vector_type(4))) float f4v;
typedef __attribute__((ext_vector_type(4))) unsigned short us4v;

__device__ __forceinline__ void split2(float v, unsigned short &h, unsigned short &l){
  _Float16 hf = (_Float16)v;
  _Float16 lf = (_Float16)((v - (float)hf) * 2048.0f);
  h = __builtin_bit_cast(unsigned short, hf);
  l = __builtin_bit_cast(unsigned short, lf);
}

__device__ __forceinline__ void gload16(const void* g, void* l){
  __builtin_amdgcn_global_load_lds(
      (const __attribute__((address_space(1))) void*)g,
      (__attribute__((address_space(3))) void*)l, 16, 0, 0);
}

// ===========================================================================
// split kernels
// ===========================================================================
__global__ __launch_bounds__(256)
void splitX(const float* __restrict__ x, const float* __restrict__ bdec,
            unsigned short* __restrict__ p0, unsigned short* __restrict__ p1)
{
  const size_t i = ((size_t)blockIdx.x * 256 + threadIdx.x) * 4;
  const int col = (int)(i & (DIM - 1));
  const float4 v = *(const float4*)(x + i);
  const float4 b = *(const float4*)(bdec + col);
  float e0 = v.x - b.x, e1 = v.y - b.y, e2 = v.z - b.z, e3 = v.w - b.w;
  ushort4 H, L;
  split2(e0, H.x, L.x); split2(e1, H.y, L.y);
  split2(e2, H.z, L.z); split2(e3, H.w, L.w);
  *(ushort4*)(p0 + i) = H; *(ushort4*)(p1 + i) = L;
}

// fused weight split: y=0 -> Wk1 (hi+lo), y=1 -> Wenc (hi only)
__global__ __launch_bounds__(256)
void splitWs(const float* __restrict__ wk1src, const float* __restrict__ wencsrc,
             unsigned short* __restrict__ wk0, unsigned short* __restrict__ wk1lo,
             unsigned short* __restrict__ we0)
{
  const size_t i = ((size_t)blockIdx.x * 256 + threadIdx.x) * 4;
  if (blockIdx.y == 0){
    const float4 v = *(const float4*)(wk1src + i);
    ushort4 H, L;
    split2(v.x, H.x, L.x); split2(v.y, H.y, L.y);
    split2(v.z, H.z, L.z); split2(v.w, H.w, L.w);
    *(ushort4*)(wk0 + i) = H; *(ushort4*)(wk1lo + i) = L;
  } else {
    const float4 v = *(const float4*)(wencsrc + i);
    ushort4 H;
    H.x = __builtin_bit_cast(unsigned short, (_Float16)v.x);
    H.y = __builtin_bit_cast(unsigned short, (_Float16)v.y);
    H.z = __builtin_bit_cast(unsigned short, (_Float16)v.z);
    H.w = __builtin_bit_cast(unsigned short, (_Float16)v.w);
    *(ushort4*)(we0 + i) = H;
  }
}

// ===========================================================================
// Fused dual 1-product GEMM, r11-proven role-split structure:
// 512 threads / 8 waves; waves 0-3: acts (C1=A*B1^T), waves 4-7: kest
// (C2=A*B2^T). Wave tile 64x64, 8 frags -> 16 MFMA. 48 KB LDS dbuf,
// staging = 24 x 1KB chunks (3/wave). acts stored fp16.
// ===========================================================================
__global__ __launch_bounds__(512, 3)
void gemmd(const unsigned short* __restrict__ Ah_, const unsigned short* __restrict__ B1h_,
           const unsigned short* __restrict__ B2h_,
           const float* __restrict__ benc, const float* __restrict__ bk1,
           const float* __restrict__ w2,
           _Float16* __restrict__ acts16, float* __restrict__ zpart)
{
  __shared__ unsigned short sAB[2][3][128][32];   // 48 KB: [buf][A|B1|B2]
  const int tid  = threadIdx.x;
  const int lane = tid & 63, wv = tid >> 6;       // wv 0..7

  const int bid = blockIdx.x;
  const int xcd = bid & 7;
  const int idx = bid >> 3;
  const int sq  = idx >> 6;
  const int s   = idx & 63;
  const int bx  = (xcd << 4) | ((sq & 1) << 3) | (s & 7);
  const int by  = ((sq >> 1) << 3) | (s >> 3);
  const int row0 = by << 7, col0 = bx << 7;

  const int role = wv >> 2;                 // 0: acts, 1: kest
  const int wloc = wv & 3;
  const int wr = (wloc & 1) << 6, wc = (wloc >> 1) << 6;

  f4v acc[4][4];
  #pragma unroll
  for (int i = 0; i < 4; ++i)
    #pragma unroll
    for (int j = 0; j < 4; ++j)
      acc[i][j] = (f4v){0.f, 0.f, 0.f, 0.f};

  // staging: 24 chunks of 1 KB (8 A + 8 B1 + 8 B2); 3 per wave
  const unsigned short* gsrc[3];
  unsigned ldsoff[3];
  #pragma unroll
  for (int j = 0; j < 3; ++j){
    const int q = wv * 3 + j;          // 0..23
    const int mat = q >> 3;            // 0=A, 1=B1, 2=B2
    const int chunk = q & 7;
    const int r  = (chunk << 4) + (lane >> 2);      // 0..127
    const int gl = (lane & 3) ^ ((r >> 1) & 3);
    const int rowg = ((mat == 0) ? row0 : col0) + r;
    const unsigned short* P = (mat == 0) ? Ah_ : ((mat == 1) ? B1h_ : B2h_);
    gsrc[j]  = P + (size_t)rowg * DIM + (gl << 3);
    ldsoff[j] = (unsigned)(mat * 8192 + chunk * 1024);
  }

  const int fr16 = lane & 15;
  const int kg   = lane >> 4;
  const int bmat = 1 + role;
  int ra[4], rb[4];
  #pragma unroll
  for (int f = 0; f < 4; ++f){ ra[f] = wr + (f << 4) + fr16; rb[f] = wc + (f << 4) + fr16; }

  #define LDFRAGD(bf, mat, r) \
    (*(const h8v*)((const char*)sAB + (bf) * 24576 + (mat) * 8192 + (r) * 64 + (((kg ^ (((r) >> 1) & 3)) << 4))))
  #define STAGED(bf, ko)                                                      \
    {                                                                         \
      _Pragma("unroll")                                                       \
      for (int j = 0; j < 3; ++j)                                             \
        gload16(gsrc[j] + (ko), (char*)sAB + (bf) * 24576 + ldsoff[j]);       \
    }

  int cur = 0;
  STAGED(0, 0);
  __syncthreads();

  for (int kt = 0; kt < DIM / 32; ++kt){
    if (kt < DIM / 32 - 1) STAGED(cur ^ 1, (kt + 1) << 5);

    h8v Ahf[4], Bhf[4];
    #pragma unroll
    for (int f = 0; f < 4; ++f) Ahf[f] = LDFRAGD(cur, 0, ra[f]);
    #pragma unroll
    for (int f = 0; f < 4; ++f) Bhf[f] = LDFRAGD(cur, bmat, rb[f]);
    #pragma unroll
    for (int fi = 0; fi < 4; ++fi)
      #pragma unroll
      for (int fj = 0; fj < 4; ++fj)
        acc[fi][fj] = __builtin_amdgcn_mfma_f32_16x16x32_f16(Bhf[fj], Ahf[fi], acc[fi][fj], 0, 0, 0);

    __syncthreads();
    cur ^= 1;
  }
  #undef LDFRAGD
  #undef STAGED

  const int mloc = lane & 15;
  const int nq   = (lane >> 4) << 2;
  if (role == 0){
    // acts epilogue (fp16 store)
    #pragma unroll
    for (int fi = 0; fi < 4; ++fi){
      const int grow = row0 + wr + (fi << 4) + mloc;
      #pragma unroll
      for (int fj = 0; fj < 4; ++fj){
        const int gcol = col0 + wc + (fj << 4) + nq;
        const float4 be = *(const float4*)(benc + gcol);
        us4v h;
        h[0] = __builtin_bit_cast(unsigned short, (_Float16)fmaxf(acc[fi][fj][0] + be.x, 0.f));
        h[1] = __builtin_bit_cast(unsigned short, (_Float16)fmaxf(acc[fi][fj][1] + be.y, 0.f));
        h[2] = __builtin_bit_cast(unsigned short, (_Float16)fmaxf(acc[fi][fj][2] + be.z, 0.f));
        h[3] = __builtin_bit_cast(unsigned short, (_Float16)fmaxf(acc[fi][fj][3] + be.w, 0.f));
        __builtin_nontemporal_store(h, (us4v*)(acts16 + (size_t)grow * FEAT + gcol));
      }
    }
  } else {
    // kest epilogue
    #pragma unroll
    for (int fi = 0; fi < 4; ++fi){
      float ssum = 0.f;
      #pragma unroll
      for (int fj = 0; fj < 4; ++fj){
        const int gcol = col0 + wc + (fj << 4) + nq;
        const float4 be = *(const float4*)(bk1 + gcol);
        const float4 wk = *(const float4*)(w2 + gcol);
        float h0 = fmaxf(acc[fi][fj][0] + be.x, 0.f);
        float h1 = fmaxf(acc[fi][fj][1] + be.y, 0.f);
        float h2 = fmaxf(acc[fi][fj][2] + be.z, 0.f);
        float h3 = fmaxf(acc[fi][fj][3] + be.w, 0.f);
        ssum = fmaf(h0, wk.x, ssum);
        ssum = fmaf(h1, wk.y, ssum);
        ssum = fmaf(h2, wk.z, ssum);
        ssum = fmaf(h3, wk.w, ssum);
      }
      ssum += __shfl_xor(ssum, 16);
      ssum += __shfl_xor(ssum, 32);
      if (lane < 16){
        const int grow = row0 + wr + (fi << 4) + lane;
        zpart[(size_t)grow * 256 + (bx << 1) + (wc >> 6)] = ssum;
      }
    }
  }
}

// ===========================================================================
// Exact kest GEMM on GATHERED flagged rows (3-product fp32-equivalent).
// ===========================================================================
__global__ __launch_bounds__(512, 4)
void gemmx(const unsigned short* __restrict__ Ah_, const unsigned short* __restrict__ Al_,
           const unsigned short* __restrict__ Bh_, const unsigned short* __restrict__ Bl_,
           const float* __restrict__ bias, const float* __restrict__ w2,
           const int* __restrict__ rowList, const int* __restrict__ nflagp,
           float* __restrict__ zexact)
{
  const int panel = blockIdx.x >> 7;          // 0..15
  const int bx    = blockIdx.x & 127;
  const int row0p = panel << 7;
  if (row0p >= *nflagp) return;
  const int col0 = bx << 7;

  __shared__ unsigned short sAB[2][2][128][64];
  const int tid  = threadIdx.x;
  const int lane = tid & 63, wv = tid >> 6;
  const int wr = (wv & 3) << 5, wc = (wv >> 2) << 6;

  f4v acc[2][4], acc2[2][4];
  #pragma unroll
  for (int i = 0; i < 2; ++i)
    #pragma unroll
    for (int j = 0; j < 4; ++j){
      acc[i][j]  = (f4v){0.f, 0.f, 0.f, 0.f};
      acc2[i][j] = (f4v){0.f, 0.f, 0.f, 0.f};
    }

  const unsigned short* gsrc[4];
  unsigned ldsoff[4];
  #pragma unroll
  for (int j = 0; j < 4; ++j){
    const int q = (wv << 2) + j;
    const int mat = q >> 4;
    const int chunk = q & 15;
    const int r  = (chunk << 3) + (lane >> 3);
    const int gl = (lane & 7) ^ (r & 7);
    const int co = (gl & 3) << 3;
    const unsigned short* hi = (mat == 0) ? Ah_ : Bh_;
    const unsigned short* lo = (mat == 0) ? Al_ : Bl_;
    const int rowg = (mat == 0) ? rowList[row0p + r] : (col0 + r);
    gsrc[j]  = ((gl < 4) ? hi : lo) + (size_t)rowg * DIM + co;
    ldsoff[j] = (unsigned)(mat * 16384 + chunk * 1024);
  }

  const int fr16 = lane & 15;
  const int kg   = lane >> 4;
  int ra[2], rb[4];
  #pragma unroll
  for (int f = 0; f < 2; ++f) ra[f] = wr + (f << 4) + fr16;
  #pragma unroll
  for (int f = 0; f < 4; ++f) rb[f] = wc + (f << 4) + fr16;

  #define LDFRAG(bf, mat, r, hb) \
    (*(const h8v*)((const char*)sAB + (bf) * 32768 + (mat) * 16384 + (r) * 128 + (((((hb) + kg) ^ ((r) & 7)) << 4))))
  #define STAGE(bf, ko)                                                       \
    {                                                                         \
      _Pragma("unroll")                                                       \
      for (int j = 0; j < 4; ++j)                                             \
        gload16(gsrc[j] + (ko), (char*)sAB + (bf) * 32768 + ldsoff[j]);       \
    }

  int cur = 0;
  STAGE(0, 0);
  __syncthreads();

  for (int kt = 0; kt < DIM / 32; ++kt){
    if (kt < DIM / 32 - 1) STAGE(cur ^ 1, (kt + 1) << 5);

    h8v Ahf[2], Bhf[4], Xl[4];
    #pragma unroll
    for (int f = 0; f < 2; ++f) Ahf[f] = LDFRAG(cur, 0, ra[f], 0);
    #pragma unroll
    for (int f = 0; f < 4; ++f) Bhf[f] = LDFRAG(cur, 1, rb[f], 0);
    #pragma unroll
    for (int fi = 0; fi < 2; ++fi)
      #pragma unroll
      for (int fj = 0; fj < 4; ++fj)
        acc[fi][fj] = __builtin_amdgcn_mfma_f32_16x16x32_f16(Bhf[fj], Ahf[fi], acc[fi][fj], 0, 0, 0);
    #pragma unroll
    for (int f = 0; f < 2; ++f) Xl[f] = LDFRAG(cur, 0, ra[f], 4);
    #pragma unroll
    for (int fi = 0; fi < 2; ++fi)
      #pragma unroll
      for (int fj = 0; fj < 4; ++fj)
        acc2[fi][fj] = __builtin_amdgcn_mfma_f32_16x16x32_f16(Bhf[fj], Xl[fi], acc2[fi][fj], 0, 0, 0);
    #pragma unroll
    for (int f = 0; f < 4; ++f) Xl[f] = LDFRAG(cur, 1, rb[f], 4);
    #pragma unroll
    for (int fi = 0; fi < 2; ++fi)
      #pragma unroll
      for (int fj = 0; fj < 4; ++fj)
        acc2[fi][fj] = __builtin_amdgcn_mfma_f32_16x16x32_f16(Xl[fj], Ahf[fi], acc2[fi][fj], 0, 0, 0);

    __syncthreads();
    cur ^= 1;
  }
  #undef LDFRAG
  #undef STAGE

  const float LSC = 1.0f / 2048.0f;
  const int nq = (lane >> 4) << 2;
  #pragma unroll
  for (int fi = 0; fi < 2; ++fi){
    float ssum = 0.f;
    #pragma unroll
    for (int fj = 0; fj < 4; ++fj){
      const int gcol = col0 + wc + (fj << 4) + nq;
      const float4 be = *(const float4*)(bias + gcol);
      const float4 wk = *(const float4*)(w2 + gcol);
      float h0 = fmaxf(acc[fi][fj][0] + LSC * acc2[fi][fj][0] + be.x, 0.f);
      float h1 = fmaxf(acc[fi][fj][1] + LSC * acc2[fi][fj][1] + be.y, 0.f);
      float h2 = fmaxf(acc[fi][fj][2] + LSC * acc2[fi][fj][2] + be.z, 0.f);
      float h3 = fmaxf(acc[fi][fj][3] + LSC * acc2[fi][fj][3] + be.w, 0.f);
      ssum = fmaf(h0, wk.x, ssum);
      ssum = fmaf(h1, wk.y, ssum);
      ssum = fmaf(h2, wk.z, ssum);
      ssum = fmaf(h3, wk.w, ssum);
    }
    ssum += __shfl_xor(ssum, 16);
    ssum += __shfl_xor(ssum, 32);
    if (lane < 16){
      const int pos = row0p + wr + (fi << 4) + lane;
      zexact[(size_t)pos * 256 + (bx << 1) + (wc >> 6)] = ssum;
    }
  }
}

// ===========================================================================
// tail kernels
// ===========================================================================
__global__ __launch_bounds__(256)
void zinit(int* __restrict__ rowList, int* __restrict__ nflag)
{
  const int i = blockIdx.x * 256 + threadIdx.x;
  if (i < MAXF) rowList[i] = 0;
  if (i == 0) *nflag = 0;
}

__global__ __launch_bounds__(256)
void zreduce_flag(const float* __restrict__ zpart, const float* __restrict__ bk2,
                  const int* __restrict__ kp, int* __restrict__ mrow,
                  int* __restrict__ rowList, int* __restrict__ nflag)
{
  const int row  = blockIdx.x * 4 + (threadIdx.x >> 6);
  const int lane = threadIdx.x & 63;
  const float* zp = zpart + (size_t)row * 256;
  float s = zp[lane] + zp[lane + 64] + zp[lane + 128] + zp[lane + 192];
  s += __shfl_xor(s, 1);
  s += __shfl_xor(s, 2);
  s += __shfl_xor(s, 4);
  s += __shfl_xor(s, 8);
  s += __shfl_xor(s, 16);
  s += __shfl_xor(s, 32);
  if (lane == 0){
    float z = s + bk2[0];
    float kest = 2.f * (float)(*kp) * (1.f / (1.f + expf(-z)));
    int m = (int)ceilf(kest);
    m = min(max(m, 0), 128);
    mrow[row] = m;
    const float frac = kest - floorf(kest);
    const float dmin = fminf(frac, 1.f - frac);
    // 0.1 band (proven r10-r15): >=2x worst-case 1-product fp16 kest error
    if (dmin < 0.1f){
      int p = atomicAdd(nflag, 1);
      if (p < MAXF) rowList[p] = row;
    }
  }
}

__global__ __launch_bounds__(256)
void zreduce2(const float* __restrict__ zexact, const int* __restrict__ rowList,
              const int* __restrict__ nflagp, const float* __restrict__ bk2,
              const int* __restrict__ kp, int* __restrict__ mrow)
{
  const int pos  = blockIdx.x * 4 + (threadIdx.x >> 6);
  const int lane = threadIdx.x & 63;
  const int nf = min(*nflagp, MAXF);
  if (pos >= nf) return;
  const float* zp = zexact + (size_t)pos * 256;
  float s = zp[lane] + zp[lane + 64] + zp[lane + 128] + zp[lane + 192];
  s += __shfl_xor(s, 1);
  s += __shfl_xor(s, 2);
  s += __shfl_xor(s, 4);
  s += __shfl_xor(s, 8);
  s += __shfl_xor(s, 16);
  s += __shfl_xor(s, 32);
  if (lane == 0){
    float z = s + bk2[0];
    float kest = 2.f * (float)(*kp) * (1.f / (1.f + expf(-z)));
    int m = (int)ceilf(kest);
    m = min(max(m, 0), 128);
    mrow[rowList[pos]] = m;
  }
}

__device__ __forceinline__ void radix_find(int* hist, int nbins, int need, int tid,
                                           int* out3, int* blksum)
{
  const int per  = nbins >> 8;
  const int base = tid * per;
  int bs = 0;
  for (int j = 0; j < per; ++j) bs += hist[base + j];
  blksum[tid] = bs;
  __syncthreads();
  if (tid == 0){
    int a2 = 0;
    for (int t = 255; t >= 0; --t){ int v = blksum[t]; blksum[t] = a2; a2 += v; }
  }
  __syncthreads();
  int ch = blksum[tid];
  for (int j = per - 1; j >= 0; --j){
    const int b = base + j;
    const int c = hist[b];
    if (ch < need && need <= ch + c){ out3[0] = b; out3[1] = need - ch; out3[2] = ch; }
    ch += c;
  }
  __syncthreads();
}

// Band select on fp16 approx acts (proven r13-r15)
__global__ __launch_bounds__(256)
void select_band(const _Float16* __restrict__ acts16, const float* __restrict__ x,
                 const float* __restrict__ bdec, const float* __restrict__ Wenc,
                 const int* __restrict__ mrow, int* __restrict__ selIdx,
                 float* __restrict__ selVal, int* __restrict__ scount)
{
  __shared__ int hist[2048];        // later reused as float xcs[2048]
  __shared__ int blksum[256];
  __shared__ int out3[4];
  __shared__ unsigned short listU[2048];
  __shared__ int listI[2048];
  __shared__ int h32[32];
  __shared__ int lcnt, dcnt, acnt;
  __shared__ unsigned short ambU[64];
  __shared__ int ambI[64];
  __shared__ double ambE[64];
  __shared__ double wred[4];

  const int row = blockIdx.x, tid = threadIdx.x;
  const int m = mrow[row];
  const unsigned short* rp = (const unsigned short*)(acts16 + (size_t)row * FEAT);
  const int base = row << 7;

  for (int i = tid; i < 2048; i += 256) hist[i] = 0;
  __syncthreads();
  // pass 1: hist of u16 >> 5 (8 fp16 per uint4 read)
  for (int it = 0; it < 8; ++it){
    const int i8 = (it << 8) + tid;               // 0..2047
    const uint4 u4 = *(const uint4*)(rp + i8 * 8);
    #pragma unroll
    for (int w = 0; w < 4; ++w){
      const unsigned ww = (&u4.x)[w];
      const unsigned a = ww & 0xFFFFu, b = ww >> 16;
      if (a) atomicAdd(&hist[a >> 5], 1);
      if (b) atomicAdd(&hist[b >> 5], 1);
    }
  }
  __syncthreads();
  radix_find(hist, 2048, m, tid, out3, blksum);
  const int bin1 = out3[0];
  const int rem1 = out3[1];
  const int bin1m1 = (bin1 > 1) ? bin1 - 1 : 1;

  if (tid == 0){ lcnt = 0; dcnt = 0; acnt = 0; }
  if (tid < 32) h32[tid] = 0;
  __syncthreads();
  // pass 2: collect (u16, idx) for bins >= bin1-1
  for (int it = 0; it < 8; ++it){
    const int i8 = (it << 8) + tid;
    const uint4 u4 = *(const uint4*)(rp + i8 * 8);
    const int ib = i8 << 3;
    #pragma unroll
    for (int w = 0; w < 4; ++w){
      const unsigned ww = (&u4.x)[w];
      const unsigned a = ww & 0xFFFFu, b = ww >> 16;
      if ((int)(a >> 5) >= bin1m1){
        int p = atomicAdd(&lcnt, 1);
        if (p < 2048){ listU[p] = (unsigned short)a; listI[p] = ib + 2 * w; }
      }
      if ((int)(b >> 5) >= bin1m1){
        int p = atomicAdd(&lcnt, 1);
        if (p < 2048){ listU[p] = (unsigned short)b; listI[p] = ib + 2 * w + 1; }
      }
    }
  }
  __syncthreads();
  const int L = min(lcnt, 2048);

  // exact vm: rem1-th largest low-5-bit value among bin1 elements
  for (int i = tid; i < L; i += 256){
    const unsigned u = listU[i];
    if ((int)(u >> 5) == bin1) atomicAdd(&h32[u & 31], 1);
  }
  __syncthreads();
  if (tid == 0){
    int c = 0, b3 = 0;
    for (int j = 31; j >= 0; --j){
      c += h32[j];
      if (c >= rem1){ b3 = j; break; }
    }
    out3[3] = b3;
  }
  __syncthreads();
  const unsigned short vm16 = (unsigned short)(((unsigned)bin1 << 5) | (unsigned)out3[3]);
  const float vmf = (float)__builtin_bit_cast(_Float16, vm16);
  const float EPS2 = 0.01f;
  const float lo_cut = vmf - EPS2, hi_cut = vmf + EPS2;

  for (int i = tid; i < L; i += 256){
    const float f = (float)__builtin_bit_cast(_Float16, listU[i]);
    if (f > hi_cut){
      int p = atomicAdd(&dcnt, 1);
      selIdx[base + p] = listI[i];
      selVal[base + p] = f;
    } else if (f >= lo_cut){
      int p = atomicAdd(&acnt, 1);
      if (p < 64){ ambU[p] = listU[i]; ambI[p] = listI[i]; }
    }
  }
  __syncthreads();
  const int D = dcnt;
  const int A = min(acnt, 64);
  int need = m - D;
  if (need < 0) need = 0;
  if (need > A) need = A;

  if (need > 0){
    float* xcs = (float*)hist;
    for (int j = tid; j < DIM; j += 256)
      xcs[j] = x[(size_t)row * DIM + j] - bdec[j];
    __syncthreads();
    const int lane = tid & 63, wv = tid >> 6;
    for (int c = 0; c < A; ++c){
      const float* wrow = Wenc + (size_t)ambI[c] * DIM;
      double sd = 0.0;
      for (int j = tid; j < DIM; j += 256)
        sd += (double)xcs[j] * (double)wrow[j];
      #pragma unroll
      for (int off = 32; off; off >>= 1) sd += __shfl_xor(sd, off);
      if (lane == 0) wred[wv] = sd;
      __syncthreads();
      if (tid == 0) ambE[c] = wred[0] + wred[1] + wred[2] + wred[3];
      __syncthreads();
    }
    if (tid == 0){
      for (int e = 0; e < need; ++e){
        int best = -1;
        for (int c = 0; c < A; ++c){
          if (ambI[c] < 0) continue;
          if (best < 0 || ambE[c] > ambE[best] ||
              (ambE[c] == ambE[best] && ambI[c] < ambI[best])) best = c;
        }
        selIdx[base + D + e] = ambI[best];
        selVal[base + D + e] = (float)__builtin_bit_cast(_Float16, ambU[best]);
        ambI[best] = -1;
      }
    }
  }
  if (tid == 0) scount[row] = D + need;
}

// W_dec [DIM][FEAT] fp32 -> WdT16 [FEAT][DIM] fp16
__global__ __launch_bounds__(256)
void transpose_dec(const float* __restrict__ Wd, _Float16* __restrict__ WdT16)
{
  __shared__ float t[64][65];
  const int f0 = blockIdx.x << 6, d0 = blockIdx.y << 6;
  const int tx = threadIdx.x & 15, ty = threadIdx.x >> 4;
  #pragma unroll
  for (int r = 0; r < 4; ++r){
    const int d = ty + (r << 4);
    const float4 v = *(const float4*)(Wd + (size_t)(d0 + d) * FEAT + f0 + (tx << 2));
    t[d][(tx << 2) + 0] = v.x;
    t[d][(tx << 2) + 1] = v.y;
    t[d][(tx << 2) + 2] = v.z;
    t[d][(tx << 2) + 3] = v.w;
  }
  __syncthreads();
  #pragma unroll
  for (int r = 0; r < 4; ++r){
    const int f = ty + (r << 4);
    ushort4 o;
    o.x = __builtin_bit_cast(unsigned short, (_Float16)t[(tx << 2) + 0][f]);
    o.y = __builtin_bit_cast(unsigned short, (_Float16)t[(tx << 2) + 1][f]);
    o.z = __builtin_bit_cast(unsigned short, (_Float16)t[(tx << 2) + 2][f]);
    o.w = __builtin_bit_cast(unsigned short, (_Float16)t[(tx << 2) + 3][f]);
    *(ushort4*)(WdT16 + (size_t)(f0 + f) * DIM + d0 + (tx << 2)) = o;
  }
}

__global__ __launch_bounds__(256)
void decode_k(const _Float16* __restrict__ WdT16, const int* __restrict__ selIdx,
              const float* __restrict__ selVal, const int* __restrict__ scount,
              const float* __restrict__ bdec, float* __restrict__ out)
{
  __shared__ int   sI[128];
  __shared__ float sV[128];
  const int row = blockIdx.x, tid = threadIdx.x;
  const int m = scount[row];
  if (tid < m){
    sI[tid] = selIdx[(row << 7) + tid];
    sV[tid] = selVal[(row << 7) + tid];
  }
  __syncthreads();
  const int d = tid << 3;
  float a[8];
  {
    const float4 b0 = *(const float4*)(bdec + d);
    const float4 b1 = *(const float4*)(bdec + d + 4);
    a[0] = b0.x; a[1] = b0.y; a[2] = b0.z; a[3] = b0.w;
    a[4] = b1.x; a[5] = b1.y; a[6] = b1.z; a[7] = b1.w;
  }
  for (int i = 0; i < m; ++i){
    const float v = sV[i];
    const h8v w = *(const h8v*)(WdT16 + (size_t)sI[i] * DIM + d);
    #pragma unroll
    for (int j = 0; j < 8; ++j)
      a[j] = fmaf(v, (float)w[j], a[j]);
  }
  float4 o0 = {a[0], a[1], a[2], a[3]};
  float4 o1 = {a[4], a[5], a[6], a[7]};
  *(float4*)(out + (size_t)row * DIM + d)     = o0;
  *(float4*)(out + (size_t)row * DIM + d + 4) = o1;
}

// ===========================================================================
extern "C" void kernel_launch(void* const* d_in, const int* in_sizes, int n_in,
                              void* d_out, int out_size, void* d_ws, size_t ws_size,
                              hipStream_t stream)
{
  const float* x    = (const float*)d_in[0];
  const float* Wenc = (const float*)d_in[1];
  const float* benc = (const float*)d_in[2];
  const float* Wk1  = (const float*)d_in[3];
  const float* bk1  = (const float*)d_in[4];
  const float* Wk2  = (const float*)d_in[5];
  const float* bk2  = (const float*)d_in[6];
  const float* Wdec = (const float*)d_in[7];
  const float* bdec = (const float*)d_in[8];
  const int*   kp   = (const int*)d_in[9];
  float* out = (float*)d_out;

  char* ws = (char*)d_ws;
  const size_t XS_BYTES   = (size_t)BATCH * DIM * 2;      // 16 MB per plane
  const size_t ACTS_BYTES = (size_t)BATCH * FEAT * 4;     // keep 256 MB reservation
  const size_t WP_BYTES   = (size_t)FEAT * DIM * 2;       // 64 MB per plane

  unsigned short* xs0 = (unsigned short*)ws;
  unsigned short* xs1 = (unsigned short*)(ws + XS_BYTES);
  char* p = ws + 2 * XS_BYTES;
  _Float16* acts16 = (_Float16*)p;         // 128 MB used
  _Float16* WdT16  = (_Float16*)p;         // aliased after select (64 MB)
  p += ACTS_BYTES;
  unsigned short* wk0 = (unsigned short*)p;                   // Wk1 hi
  unsigned short* wk1 = (unsigned short*)(p + WP_BYTES);      // Wk1 lo
  unsigned short* we0 = (unsigned short*)(p + 2 * WP_BYTES);  // Wenc hi
  p += 3 * WP_BYTES;
  float* zpart  = (float*)p;               p += 4194304;
  int*   mrow   = (int*)p;                 p += 16384;
  int*   selIdx = (int*)p;                 p += 2097152;
  float* selVal = (float*)p;               p += 2097152;
  int*   scount = (int*)p;                 p += 16384;
  int*   rowList= (int*)p;                 p += MAXF * 4;
  int*   nflag  = (int*)p;                 p += 128;
  float* zexact = (float*)p;               p += (size_t)MAXF * 256 * 4;

  (void)ws_size; (void)in_sizes; (void)n_in; (void)out_size;

  zinit<<<dim3(MAXF / 256), dim3(256), 0, stream>>>(rowList, nflag);
  splitX<<<dim3(BATCH * DIM / 1024), dim3(256), 0, stream>>>(x, bdec, xs0, xs1);
  splitWs<<<dim3(FEAT * DIM / 1024, 2), dim3(256), 0, stream>>>(Wk1, Wenc, wk0, wk1, we0);
  // fused dual GEMM: acts16 (approx) + kest zpart (approx)
  gemmd<<<dim3(4096), dim3(512), 0, stream>>>(xs0, we0, wk0, benc, bk1, Wk2,
                                              acts16, zpart);
  zreduce_flag<<<dim3(BATCH / 4), dim3(256), 0, stream>>>(zpart, bk2, kp, mrow,
                                                          rowList, nflag);
  // exact recompute of flagged rows only
  gemmx<<<dim3(16 * 128), dim3(512), 0, stream>>>(xs0, xs1, wk0, wk1, bk1, Wk2,
                                                  rowList, nflag, zexact);
  zreduce2<<<dim3(MAXF / 4), dim3(256), 0, stream>>>(zexact, rowList, nflag,
                                                     bk2, kp, mrow);
  select_band<<<dim3(BATCH), dim3(256), 0, stream>>>(acts16, x, bdec, Wenc, mrow,
                                                     selIdx, selVal, scount);
  transpose_dec<<<dim3(FEAT / 64, DIM / 64), dim3(256), 0, stream>>>(Wdec, WdT16);
  decode_k<<<dim3(BATCH), dim3(256), 0, stream>>>(WdT16, selIdx, selVal, scount, bdec, out);
}